// Round 1
// baseline (90.217 us; speedup 1.0000x reference)
//
#include <hip/hip_runtime.h>
#include <math.h>

#define NCLUST 32
#define NPTS   1000000
#define LOG2E  1.4426950408889634f
#define TWO_PI 6.2831853071795864f

// ws layout (floats):
//   ws[0]            = S accumulator (sum over points of (sum_k w_k dens)^2)
//   ws[1]            = Z (pairwise term)
//   ws[2..3]         = pad
//   ws[4 + k*8 + i]  = per-cluster folded constants, stride 8:
//     [0]=a (coef xx) [1]=b (xy) [2]=c (yy) [3]=e (x) [4]=f (y) [5]=W  [6,7]=0
//   with a,b,c,e,f pre-scaled by -0.5*log2(e) so dens*w = W * exp2(a*xx+b*xy+c*yy+e*x+f*y)

__global__ void nmsq_setup(const float* __restrict__ means,
                           const float* __restrict__ chols,
                           const float* __restrict__ weights,
                           float* __restrict__ ws) {
    __shared__ float sL00[NCLUST], sL10[NCLUST], sL11[NCLUST];
    __shared__ float sM0[NCLUST], sM1[NCLUST], sW[NCLUST];
    __shared__ float red[4];
    const int t = threadIdx.x;

    if (t < NCLUST) {
        // tril(chols) for D=2: [[c00,0],[c10,c11]]
        float c00 = chols[t * 4 + 0];
        float c10 = chols[t * 4 + 2];
        float c11 = chols[t * 4 + 3];
        // S = tril @ tril^T + I
        float S00 = fmaf(c00, c00, 1.0f);
        float S10 = c00 * c10;
        float S11 = c10 * c10 + c11 * c11 + 1.0f;
        // L = cholesky(S), lower
        float L00 = sqrtf(S00);
        float L10 = S10 / L00;
        float L11 = sqrtf(S11 - L10 * L10);
        float m0 = means[t * 2 + 0];
        float m1 = means[t * 2 + 1];
        float w  = weights[t];
        sL00[t] = L00; sL10[t] = L10; sL11[t] = L11;
        sM0[t] = m0;   sM1[t] = m1;   sW[t] = w;

        // L_inv (lower tri): [[1/L00, 0], [-L10/(L00*L11), 1/L11]]
        float iL00 = 1.0f / L00;
        float iL11 = 1.0f / L11;
        float Li00 = iL00;
        float Li10 = -L10 * iL00 * iL11;
        float Li11 = iL11;
        // q = Li00*d0^2 + Li10*d0*d1 + Li11*d1^2, d = x - mu
        // fold -0.5*log2(e) and expand in x
        const float s = -0.5f * LOG2E;
        float a = s * Li00, b = s * Li10, c = s * Li11;
        float e = -(2.0f * a * m0 + b * m1);
        float f = -(b * m0 + 2.0f * c * m1);
        float g = a * m0 * m0 + b * m0 * m1 + c * m1 * m1;
        // norm_const = sqrt((2pi)^2 * det(L)) = 2pi*sqrt(L00*L11)
        float invnorm = 1.0f / (TWO_PI * sqrtf(L00 * L11));
        float W = w * invnorm * exp2f(g);
        float* cp = ws + 4 + t * 8;
        cp[0] = a; cp[1] = b; cp[2] = c; cp[3] = e;
        cp[4] = f; cp[5] = W; cp[6] = 0.0f; cp[7] = 0.0f;
    }
    if (t == 0) ws[0] = 0.0f;  // zero S accumulator (ws is 0xAA-poisoned)
    __syncthreads();

    // Z = sum_ij z_term(i,j) w_i w_j over all 1024 pairs
    float zp = 0.0f;
    for (int p = t; p < NCLUST * NCLUST; p += blockDim.x) {
        int i = p >> 5, j = p & 31;
        float A = sL00[i] + sL00[j];          // L_sum lower-tri entries
        float B = sL10[i] + sL10[j];
        float C = sL11[i] + sL11[j];
        float d0 = sM0[i] - sM0[j];
        float d1 = sM1[i] - sM1[j];
        float iA = 1.0f / A, iC = 1.0f / C;
        // inv([[A,0],[B,C]]) = [[1/A,0],[-B/(AC),1/C]]
        float qz = d0 * d0 * iA + d1 * d1 * iC - B * d0 * d1 * iA * iC;
        float zt = __expf(-0.5f * qz) / (TWO_PI * sqrtf(A * C));
        zp = fmaf(zt * sW[i], sW[j], zp);
    }
    #pragma unroll
    for (int off = 32; off > 0; off >>= 1) zp += __shfl_down(zp, off, 64);
    int lane = t & 63, wid = t >> 6;
    if (lane == 0) red[wid] = zp;
    __syncthreads();
    if (t == 0) ws[1] = red[0] + red[1] + red[2] + red[3];
}

__global__ __launch_bounds__(256) void nmsq_main(const float* __restrict__ X,
                                                 float* __restrict__ ws) {
    __shared__ float4 cc[NCLUST * 2];
    __shared__ float red[4];
    const int t = threadIdx.x;
    if (t < NCLUST * 2) cc[t] = ((const float4*)(ws + 4))[t];
    __syncthreads();

    const float4* X4 = (const float4*)X;     // 2 points per float4
    const int NV = NPTS / 2;                 // 500000
    const int T = gridDim.x * blockDim.x;

    float acc = 0.0f;
    for (int i = blockIdx.x * blockDim.x + t; i < NV; i += T) {
        float4 p = X4[i];
        float xxA = p.x * p.x, xyA = p.x * p.y, yyA = p.y * p.y;
        float xxB = p.z * p.z, xyB = p.z * p.w, yyB = p.w * p.w;
        float sA = 0.0f, sB = 0.0f;
        #pragma unroll
        for (int k = 0; k < NCLUST; ++k) {
            float4 c0 = cc[2 * k];
            float4 c1 = cc[2 * k + 1];
            float argA = fmaf(c0.x, xxA, fmaf(c0.y, xyA, fmaf(c0.z, yyA,
                         fmaf(c0.w, p.x, c1.x * p.y))));
            float argB = fmaf(c0.x, xxB, fmaf(c0.y, xyB, fmaf(c0.z, yyB,
                         fmaf(c0.w, p.z, c1.x * p.w))));
            sA = fmaf(c1.y, exp2f(argA), sA);
            sB = fmaf(c1.y, exp2f(argB), sB);
        }
        acc = fmaf(sA, sA, fmaf(sB, sB, acc));
    }

    #pragma unroll
    for (int off = 32; off > 0; off >>= 1) acc += __shfl_down(acc, off, 64);
    int lane = t & 63, wid = t >> 6;
    if (lane == 0) red[wid] = acc;
    __syncthreads();
    if (t == 0) atomicAdd(ws, red[0] + red[1] + red[2] + red[3]);
}

__global__ void nmsq_final(const float* __restrict__ ws, float* __restrict__ out) {
    if (threadIdx.x == 0) {
        float S = ws[0];
        float Z = ws[1];
        out[0] = -(logf(S) - logf(Z)) * (1.0f / (float)NPTS);
    }
}

extern "C" void kernel_launch(void* const* d_in, const int* in_sizes, int n_in,
                              void* d_out, int out_size, void* d_ws, size_t ws_size,
                              hipStream_t stream) {
    const float* X       = (const float*)d_in[0];
    const float* means   = (const float*)d_in[1];
    const float* chols   = (const float*)d_in[2];
    const float* weights = (const float*)d_in[3];
    // d_in[4] = it (unused)
    float* ws  = (float*)d_ws;
    float* out = (float*)d_out;

    nmsq_setup<<<1, 256, 0, stream>>>(means, chols, weights, ws);
    nmsq_main<<<1024, 256, 0, stream>>>(X, ws);
    nmsq_final<<<1, 64, 0, stream>>>(ws, out);
}

// Round 2
// 76.641 us; speedup vs baseline: 1.1771x; 1.1771x over previous
//
#include <hip/hip_runtime.h>
#include <math.h>

#define NCLUST 32
#define NPTS   1000000
#define LOG2E  1.4426950408889634f
#define TWO_PI 6.2831853071795864f
#define NBLOCKS 1024

// ws layout (floats):
//   ws[16 + b] = per-block partial sum of (sum_k w_k dens)^2  (b in [0,NBLOCKS))
// No part of ws is read before being written in the same call (ws is 0xAA-poisoned).

// Compute folded per-cluster constants for cluster t (t < NCLUST):
//   dens*w = W * exp2(a*xx + b*xy + c*yy + e*x + f*y)   (g folded into W)
__device__ inline void cluster_consts(int t,
                                      const float* __restrict__ means,
                                      const float* __restrict__ chols,
                                      const float* __restrict__ weights,
                                      float& a, float& b, float& c,
                                      float& e, float& f, float& W,
                                      float& L00, float& L10, float& L11,
                                      float& m0, float& m1, float& w) {
    float c00 = chols[t * 4 + 0];
    float c10 = chols[t * 4 + 2];
    float c11 = chols[t * 4 + 3];
    float S00 = fmaf(c00, c00, 1.0f);
    float S10 = c00 * c10;
    float S11 = c10 * c10 + c11 * c11 + 1.0f;
    L00 = sqrtf(S00);
    L10 = S10 / L00;
    L11 = sqrtf(S11 - L10 * L10);
    m0 = means[t * 2 + 0];
    m1 = means[t * 2 + 1];
    w  = weights[t];
    float iL00 = 1.0f / L00;
    float iL11 = 1.0f / L11;
    float Li00 = iL00;
    float Li10 = -L10 * iL00 * iL11;
    float Li11 = iL11;
    const float s = -0.5f * LOG2E;
    a = s * Li00; b = s * Li10; c = s * Li11;
    e = -(2.0f * a * m0 + b * m1);
    f = -(b * m0 + 2.0f * c * m1);
    float g = a * m0 * m0 + b * m0 * m1 + c * m1 * m1;
    float invnorm = 1.0f / (TWO_PI * sqrtf(L00 * L11));
    W = w * invnorm * exp2f(g);
}

__global__ __launch_bounds__(256) void nmsq_main(const float* __restrict__ X,
                                                 const float* __restrict__ means,
                                                 const float* __restrict__ chols,
                                                 const float* __restrict__ weights,
                                                 float* __restrict__ ws) {
    __shared__ float4 cc[NCLUST * 2];
    __shared__ float red[4];
    const int t = threadIdx.x;

    if (t < NCLUST) {
        float a, b, c, e, f, W, L00, L10, L11, m0, m1, w;
        cluster_consts(t, means, chols, weights, a, b, c, e, f, W,
                       L00, L10, L11, m0, m1, w);
        cc[2 * t]     = make_float4(a, b, c, e);
        cc[2 * t + 1] = make_float4(f, W, 0.0f, 0.0f);
    }
    __syncthreads();

    const float4* X4 = (const float4*)X;     // 2 points per float4
    const int NV = NPTS / 2;                 // 500000
    const int T = gridDim.x * blockDim.x;

    float acc = 0.0f;
    for (int i = blockIdx.x * blockDim.x + t; i < NV; i += T) {
        float4 p = X4[i];
        float xxA = p.x * p.x, xyA = p.x * p.y, yyA = p.y * p.y;
        float xxB = p.z * p.z, xyB = p.z * p.w, yyB = p.w * p.w;
        float sA = 0.0f, sB = 0.0f;
        #pragma unroll
        for (int k = 0; k < NCLUST; ++k) {
            float4 c0 = cc[2 * k];
            float4 c1 = cc[2 * k + 1];
            float argA = fmaf(c0.x, xxA, fmaf(c0.y, xyA, fmaf(c0.z, yyA,
                         fmaf(c0.w, p.x, c1.x * p.y))));
            float argB = fmaf(c0.x, xxB, fmaf(c0.y, xyB, fmaf(c0.z, yyB,
                         fmaf(c0.w, p.z, c1.x * p.w))));
            sA = fmaf(c1.y, __builtin_amdgcn_exp2f(argA), sA);
            sB = fmaf(c1.y, __builtin_amdgcn_exp2f(argB), sB);
        }
        acc = fmaf(sA, sA, fmaf(sB, sB, acc));
    }

    #pragma unroll
    for (int off = 32; off > 0; off >>= 1) acc += __shfl_down(acc, off, 64);
    int lane = t & 63, wid = t >> 6;
    if (lane == 0) red[wid] = acc;
    __syncthreads();
    if (t == 0) ws[16 + blockIdx.x] = red[0] + red[1] + red[2] + red[3];
}

__global__ __launch_bounds__(256) void nmsq_final(const float* __restrict__ means,
                                                  const float* __restrict__ chols,
                                                  const float* __restrict__ weights,
                                                  const float* __restrict__ ws,
                                                  float* __restrict__ out) {
    __shared__ float sL00[NCLUST], sL10[NCLUST], sL11[NCLUST];
    __shared__ float sM0[NCLUST], sM1[NCLUST], sW[NCLUST];
    __shared__ float redZ[4], redS[4];
    const int t = threadIdx.x;

    if (t < NCLUST) {
        float a, b, c, e, f, W, L00, L10, L11, m0, m1, w;
        cluster_consts(t, means, chols, weights, a, b, c, e, f, W,
                       L00, L10, L11, m0, m1, w);
        sL00[t] = L00; sL10[t] = L10; sL11[t] = L11;
        sM0[t] = m0;   sM1[t] = m1;   sW[t] = w;
    }
    __syncthreads();

    // Z over all 1024 (i,j) pairs
    float zp = 0.0f;
    for (int p = t; p < NCLUST * NCLUST; p += 256) {
        int i = p >> 5, j = p & 31;
        float A = sL00[i] + sL00[j];
        float B = sL10[i] + sL10[j];
        float C = sL11[i] + sL11[j];
        float d0 = sM0[i] - sM0[j];
        float d1 = sM1[i] - sM1[j];
        float iA = 1.0f / A, iC = 1.0f / C;
        float qz = d0 * d0 * iA + d1 * d1 * iC - B * d0 * d1 * iA * iC;
        float zt = __builtin_amdgcn_exp2f(-0.5f * LOG2E * qz) / (TWO_PI * sqrtf(A * C));
        zp = fmaf(zt * sW[i], sW[j], zp);
    }
    // S: reduce the per-block partials
    float sp = 0.0f;
    for (int i = t; i < NBLOCKS; i += 256) sp += ws[16 + i];

    #pragma unroll
    for (int off = 32; off > 0; off >>= 1) {
        zp += __shfl_down(zp, off, 64);
        sp += __shfl_down(sp, off, 64);
    }
    int lane = t & 63, wid = t >> 6;
    if (lane == 0) { redZ[wid] = zp; redS[wid] = sp; }
    __syncthreads();
    if (t == 0) {
        float Z = redZ[0] + redZ[1] + redZ[2] + redZ[3];
        float S = redS[0] + redS[1] + redS[2] + redS[3];
        out[0] = (logf(Z) - logf(S)) * (1.0f / (float)NPTS);
    }
}

extern "C" void kernel_launch(void* const* d_in, const int* in_sizes, int n_in,
                              void* d_out, int out_size, void* d_ws, size_t ws_size,
                              hipStream_t stream) {
    const float* X       = (const float*)d_in[0];
    const float* means   = (const float*)d_in[1];
    const float* chols   = (const float*)d_in[2];
    const float* weights = (const float*)d_in[3];
    // d_in[4] = it (unused)
    float* ws  = (float*)d_ws;
    float* out = (float*)d_out;

    nmsq_main<<<NBLOCKS, 256, 0, stream>>>(X, means, chols, weights, ws);
    nmsq_final<<<1, 256, 0, stream>>>(means, chols, weights, ws, out);
}